// Round 4
// baseline (273.610 us; speedup 1.0000x reference)
//
#include <hip/hip_runtime.h>

#define L_LM 2000
#define F_DIM 64
#define B_SZ 2048
#define CL 16      // landmarks per delta block
#define CB 128     // batch rows per delta block

typedef float f32x4 __attribute__((ext_vector_type(4)));

// ---------------- Kernel 1: BMU (argmin of squared distance) ----------------
__global__ __launch_bounds__(256) void som_bmu_kernel(
    const float* __restrict__ x, const float* __restrict__ lm,
    int* __restrict__ min_idx)
{
    constexpr int ROWS = 8;
    const int b0 = blockIdx.x * ROWS;
    const int tid = threadIdx.x;

    __shared__ float xs[ROWS][F_DIM];
    for (int i = tid; i < ROWS * F_DIM; i += 256) {
        xs[i / F_DIM][i % F_DIM] = x[(size_t)(b0 + i / F_DIM) * F_DIM + (i % F_DIM)];
    }
    __syncthreads();

    float best[ROWS];
    int   bidx[ROWS];
#pragma unroll
    for (int r = 0; r < ROWS; ++r) { best[r] = 3.4e38f; bidx[r] = 0; }

    for (int l = tid; l < L_LM; l += 256) {
        const float4* lp = reinterpret_cast<const float4*>(lm + (size_t)l * F_DIM);
        float dot[ROWS];
        float l2 = 0.f;
#pragma unroll
        for (int r = 0; r < ROWS; ++r) dot[r] = 0.f;
#pragma unroll
        for (int k = 0; k < F_DIM / 4; ++k) {
            float4 v = lp[k];
            l2 += v.x * v.x + v.y * v.y + v.z * v.z + v.w * v.w;
#pragma unroll
            for (int r = 0; r < ROWS; ++r) {
                dot[r] += v.x * xs[r][4 * k + 0] + v.y * xs[r][4 * k + 1]
                        + v.z * xs[r][4 * k + 2] + v.w * xs[r][4 * k + 3];
            }
        }
#pragma unroll
        for (int r = 0; r < ROWS; ++r) {
            float s = l2 - 2.f * dot[r];
            if (s < best[r]) { best[r] = s; bidx[r] = l; }  // per-thread l ascending
        }
    }

    // Wave-level reduce (64 lanes), lexicographic (score, index)
#pragma unroll
    for (int r = 0; r < ROWS; ++r) {
        float s = best[r]; int i = bidx[r];
        for (int off = 32; off > 0; off >>= 1) {
            float s2 = __shfl_down(s, off);
            int   i2 = __shfl_down(i, off);
            if (s2 < s || (s2 == s && i2 < i)) { s = s2; i = i2; }
        }
        best[r] = s; bidx[r] = i;
    }

    __shared__ float sbest[4][ROWS];
    __shared__ int   sidx[4][ROWS];
    const int wave = tid >> 6;
    const int lane = tid & 63;
    if (lane == 0) {
#pragma unroll
        for (int r = 0; r < ROWS; ++r) { sbest[wave][r] = best[r]; sidx[wave][r] = bidx[r]; }
    }
    __syncthreads();
    if (tid < ROWS) {
        float s = sbest[0][tid]; int i = sidx[0][tid];
#pragma unroll
        for (int w = 1; w < 4; ++w) {
            float s2 = sbest[w][tid]; int i2 = sidx[w][tid];
            if (s2 < s || (s2 == s && i2 < i)) { s = s2; i = i2; }
        }
        min_idx[b0 + tid] = i;
    }
}

// ---------------- Kernel 2: delta0 write (store-BW bound) ----------------
// A/B vs R3: ONLY change is plain stores instead of __builtin_nontemporal_store.
// Theory: nt policy degrades L2 write-combining -> sub-line HBM bursts
// (~4.3 TB/s observed vs 6.8 TB/s fill calibration). All reused inputs are
// registers/LDS here, so nt's anti-pollution benefit is nil for this kernel.
__global__ __launch_bounds__(256) void som_delta_kernel(
    const float* __restrict__ x, const float* __restrict__ lm,
    const float* __restrict__ qd, const int* __restrict__ min_idx,
    float* __restrict__ out)
{
    const int l0 = blockIdx.x * CL;
    const int b0 = blockIdx.y * CB;
    const int tid = threadIdx.x;
    const int f4 = tid & 15;   // float4 index within feature dim
    const int lg = tid >> 4;   // landmark offset within chunk (0..15)

    __shared__ float xs[CB][F_DIM];   // 32 KB
    __shared__ float hs[CB][CL];      // 8 KB
    __shared__ int   bmu[CB];         // 0.5 KB

    // stage x rows (coalesced float4)
    {
        const f32x4* src = reinterpret_cast<const f32x4*>(x + (size_t)b0 * F_DIM);
        f32x4* dst = reinterpret_cast<f32x4*>(&xs[0][0]);
        for (int i = tid; i < CB * F_DIM / 4; i += 256) dst[i] = src[i];
    }
    if (tid < CB) bmu[tid] = min_idx[b0 + tid];

    // thread's private landmark fragment (one float4 per thread covers chunk)
    const f32x4 lv = reinterpret_cast<const f32x4*>(lm + (size_t)(l0 + lg) * F_DIM)[f4];

    __syncthreads();

    // stage h: hs[b][j] = qd[bmu[b]][l0+j]  (64 B contiguous per b)
    for (int i = tid; i < CB * CL; i += 256) {
        const int b = i >> 4, j = i & 15;
        hs[b][j] = qd[(size_t)bmu[b] * L_LM + l0 + j];
    }
    __syncthreads();

    float* ob = out + (size_t)b0 * (L_LM * F_DIM) + (size_t)l0 * F_DIM;
#pragma unroll 4
    for (int b = 0; b < CB; ++b) {
        const float h = hs[b][lg];
        const f32x4 xv = reinterpret_cast<const f32x4*>(&xs[b][0])[f4];
        f32x4 o;
        o.x = h * (xv.x - lv.x);
        o.y = h * (xv.y - lv.y);
        o.z = h * (xv.z - lv.z);
        o.w = h * (xv.w - lv.w);
        reinterpret_cast<f32x4*>(ob + (size_t)b * (L_LM * F_DIM))[tid] = o;
    }
}

extern "C" void kernel_launch(void* const* d_in, const int* in_sizes, int n_in,
                              void* d_out, int out_size, void* d_ws, size_t ws_size,
                              hipStream_t stream) {
    const float* x  = (const float*)d_in[0];
    const float* lm = (const float*)d_in[1];
    const float* qd = (const float*)d_in[2];
    float* out = (float*)d_out;
    int* midx = (int*)d_ws;

    som_bmu_kernel<<<B_SZ / 8, 256, 0, stream>>>(x, lm, midx);

    dim3 grid(L_LM / CL, B_SZ / CB);   // (125, 16) = 2000 blocks
    som_delta_kernel<<<grid, 256, 0, stream>>>(x, lm, qd, midx, out);
}